// Round 7
// baseline (1387.555 us; speedup 1.0000x reference)
//
#include <hip/hip_runtime.h>

// Sinkhorn-Knopp, factored: s_ij = a_ij * u_i * v_j; only u,v evolve.
// R9 = R8's design with the risk surface minimized after the container
// failure (couldn't get counters; suspects were the branchy LDS/global
// phase-A store and nontemporal builtins -- both removed):
//  (1) Phase A == R7's proven pack loop (all rows -> global W0) + free
//      col-partial accumulation (fuses the initial col-only pass;
//      matrix reads 11 -> 10).
//  (2) Hybrid residency for sweeps: rows 0..127 in 32 VGPR/thread
//      (8 x uint4), rows 128..239 in a 112KB LDS copy, rows 240..511
//      from global W0. Per-sweep global reads 512KB -> 272KB/block;
//      hot L3 set 68MB << 256MB, so sweep reads should be L3 hits.
//  (3) Epilogue == R7's proven epilogue (W0 + staged chunk 15, barriers
//      for m>=8; W0 keeps ALL rows so no LDS branch needed).
#define SEPS 1e-10f
typedef unsigned int uu;

__device__ __forceinline__ uu bfpack2(float f0, float f1) {
    uu u0 = __float_as_uint(f0 + SEPS);
    uu u1 = __float_as_uint(f1 + SEPS);
    u0 += 0x7FFFu + ((u0 >> 16) & 1u);   // RNE to bf16
    u1 += 0x7FFFu + ((u1 >> 16) & 1u);
    return (u0 >> 16) | (u1 & 0xFFFF0000u);  // low16 = even col, high16 = odd col
}
__device__ __forceinline__ float blo(uu w){ return __uint_as_float(w << 16); }
__device__ __forceinline__ float bhi(uu w){ return __uint_as_float(w & 0xFFFF0000u); }
__device__ __forceinline__ float grcp(float x){ return (x > 0.f) ? __builtin_amdgcn_rcpf(x) : 1.f; }

__global__
__attribute__((amdgpu_flat_work_group_size(1024, 1024)))
void sinkhorn_kernel(const float* __restrict__ s, const int* __restrict__ nrows,
                     const int* __restrict__ ncols, float* __restrict__ out)
{
    __shared__ __align__(16) uu    w_lds[112 * 256];   // 112KB copy of W0 rows 128..239
    __shared__ __align__(16) float cpart[16][512];     // 32KB partials; epilogue stage reuse
    __shared__ float sh_u[512];
    __shared__ float sh_v[512];

    const int b   = blockIdx.x;
    const int tid = threadIdx.x;
    const int wv  = tid >> 6;    // wave 0..15
    const int wl  = tid & 63;    // lane
    const int nr  = nrows[b];
    const int nc  = ncols[b];

    float* ob = out + ((size_t)b << 18);
    uu*    W0 = (uu*)ob + 131072;            // [512 rows][256 jpair] bf16 at out+512KB
    const float4* sb4 = (const float4*)(s + ((size_t)b << 18));
    float4* ob4 = (float4*)ob;

    // ---------------- phase A: pack+mask -> W0 (all rows), fused col partials (u=1)
    {
        const int p  = tid & 127;    // float4 col index (constant per thread)
        const int t8 = tid >> 7;     // 0..7 row phase
        const int rem = nc - 4 * p;
        const uu mA = (rem >= 2) ? 0xFFFFFFFFu : ((rem == 1) ? 0x0000FFFFu : 0u);
        const uu mB = (rem >= 4) ? 0xFFFFFFFFu : ((rem == 3) ? 0x0000FFFFu : 0u);
        float cA = 0.f, cB = 0.f, cC = 0.f, cD = 0.f;
        #pragma unroll 4
        for (int k = 0; k < 64; ++k) {
            const int r = (k << 3) + t8;
            float4 w = sb4[r * 128 + p];
            const uu rm = (r < nr) ? 0xFFFFFFFFu : 0u;
            const uu px = bfpack2(w.x, w.y) & mA & rm;
            const uu py = bfpack2(w.z, w.w) & mB & rm;
            *(uint2*)(W0 + r * 256 + 2 * p) = make_uint2(px, py);
            cA += blo(px); cB += bhi(px); cC += blo(py); cD += bhi(py);
        }
        *(float4*)&cpart[t8][4 * p] = make_float4(cA, cB, cC, cD);
    }
    __syncthreads();   // W0 + cpart visible block-wide

    // ---- fill LDS copy of rows 128..239 (7168 uint4, coalesced)
    {
        const uint4* s4 = (const uint4*)(W0 + 128 * 256);
        uint4* d4 = (uint4*)w_lds;
        #pragma unroll
        for (int it = 0; it < 7; ++it)
            d4[it * 1024 + tid] = s4[it * 1024 + tid];
    }
    // ---- register rows 0..127: row 16g+wv, lane wl holds jpair quad 4wl
    const uu* wp = W0 + wl * 4;
    uint4 R0 = *(const uint4*)(wp + (  0 + wv) * 256);
    uint4 R1 = *(const uint4*)(wp + ( 16 + wv) * 256);
    uint4 R2 = *(const uint4*)(wp + ( 32 + wv) * 256);
    uint4 R3 = *(const uint4*)(wp + ( 48 + wv) * 256);
    uint4 R4 = *(const uint4*)(wp + ( 64 + wv) * 256);
    uint4 R5 = *(const uint4*)(wp + ( 80 + wv) * 256);
    uint4 R6 = *(const uint4*)(wp + ( 96 + wv) * 256);
    uint4 R7 = *(const uint4*)(wp + (112 + wv) * 256);

    if (tid < 512) {   // v1 from phase-A col partials
        float sum = cpart[0][tid] + cpart[1][tid] + cpart[2][tid] + cpart[3][tid]
                  + cpart[4][tid] + cpart[5][tid] + cpart[6][tid] + cpart[7][tid];
        sh_v[tid] = grcp(sum);
    }
    __syncthreads();   // w_lds + sh_v visible

    // fused row+col body for one row's quad wq
#define ROWF(wq) { \
    float p_ = blo(wq.x)*va.x + bhi(wq.x)*va.y + blo(wq.y)*va.z + bhi(wq.y)*va.w \
             + blo(wq.z)*vb.x + bhi(wq.z)*vb.y + blo(wq.w)*vb.z + bhi(wq.w)*vb.w; \
    p_ += __shfl_xor(p_, 1);  p_ += __shfl_xor(p_, 2);  p_ += __shfl_xor(p_, 4); \
    p_ += __shfl_xor(p_, 8);  p_ += __shfl_xor(p_, 16); p_ += __shfl_xor(p_, 32); \
    const float u_ = grcp(p_); \
    ce0 += blo(wq.x)*u_; co0 += bhi(wq.x)*u_; ce1 += blo(wq.y)*u_; co1 += bhi(wq.y)*u_; \
    ce2 += blo(wq.z)*u_; co2 += bhi(wq.z)*u_; ce3 += blo(wq.w)*u_; co3 += bhi(wq.w)*u_; }

    // ---------------- 9 fused sweeps: row(v)->u, col(u)->v'
    #pragma unroll 1
    for (int sw = 0; sw < 9; ++sw) {
        const float4 va = *(const float4*)&sh_v[wl * 8];
        const float4 vb = *(const float4*)&sh_v[wl * 8 + 4];
        float ce0=0,co0=0,ce1=0,co1=0,ce2=0,co2=0,ce3=0,co3=0;
        ROWF(R0) ROWF(R1) ROWF(R2) ROWF(R3) ROWF(R4) ROWF(R5) ROWF(R6) ROWF(R7)
        #pragma unroll
        for (int g = 8; g < 15; ++g) {
            uint4 wq = *(const uint4*)(w_lds + (16 * g + wv - 128) * 256 + wl * 4);
            ROWF(wq)
        }
        #pragma unroll 4
        for (int g = 15; g < 32; ++g) {
            uint4 wq = *(const uint4*)(wp + (16 * g + wv) * 256);
            ROWF(wq)
        }
        float* cw = &cpart[wv][wl * 8];
        cw[0]=ce0; cw[1]=co0; cw[2]=ce1; cw[3]=co1;
        cw[4]=ce2; cw[5]=co2; cw[6]=ce3; cw[7]=co3;
        __syncthreads();
        if (tid < 512) {
            float sum = 0.f;
            #pragma unroll
            for (int w = 0; w < 16; ++w) sum += cpart[w][tid];
            sh_v[tid] = grcp(sum);
        }
        __syncthreads();
    }

    // ---------------- final row-only pass: u10 from v10
#define FINROW(wq, i) { \
    float p_ = blo(wq.x)*va.x + bhi(wq.x)*va.y + blo(wq.y)*va.z + bhi(wq.y)*va.w \
             + blo(wq.z)*vb.x + bhi(wq.z)*vb.y + blo(wq.w)*vb.z + bhi(wq.w)*vb.w; \
    p_ += __shfl_xor(p_, 1);  p_ += __shfl_xor(p_, 2);  p_ += __shfl_xor(p_, 4); \
    p_ += __shfl_xor(p_, 8);  p_ += __shfl_xor(p_, 16); p_ += __shfl_xor(p_, 32); \
    if (wl == 0) sh_u[i] = grcp(p_); }
    {
        const float4 va = *(const float4*)&sh_v[wl * 8];
        const float4 vb = *(const float4*)&sh_v[wl * 8 + 4];
        FINROW(R0,   0 + wv) FINROW(R1,  16 + wv) FINROW(R2,  32 + wv) FINROW(R3,  48 + wv)
        FINROW(R4,  64 + wv) FINROW(R5,  80 + wv) FINROW(R6,  96 + wv) FINROW(R7, 112 + wv)
        #pragma unroll
        for (int g = 8; g < 15; ++g) {
            uint4 wq = *(const uint4*)(w_lds + (16 * g + wv - 128) * 256 + wl * 4);
            FINROW(wq, 16 * g + wv)
        }
        #pragma unroll 4
        for (int g = 15; g < 32; ++g) {
            uint4 wq = *(const uint4*)(wp + (16 * g + wv) * 256);
            FINROW(wq, 16 * g + wv)
        }
    }
    __syncthreads();   // sh_u visible; all sweep reads of W0 complete

    // ---------------- epilogue: out = a * u_i * v_j from W0
    // stage W0 rows 480..511 (32KB) into cpart before any overwrite
    uu* stg = (uu*)cpart;
    {
        uint4* d4 = (uint4*)stg;
        const uint4* s4 = (const uint4*)(W0 + 480 * 256);
        d4[tid]        = s4[tid];
        d4[tid + 1024] = s4[tid + 1024];
    }
    __syncthreads();
    {
        const int ep = tid & 127;   // float4 index within a row
        const int rs = tid >> 7;    // 0..7, wave-uniform
        const float4 vv = make_float4(sh_v[4*ep], sh_v[4*ep+1], sh_v[4*ep+2], sh_v[4*ep+3]);
        #pragma unroll 1
        for (int m = 0; m < 16; ++m) {
            if (m >= 8) __syncthreads();   // chunks < m done before their W0 rows die
            #pragma unroll
            for (int it = 0; it < 4; ++it) {
                const int i = (m << 5) + (it << 3) + rs;
                const uint2 tw = (m == 15)
                    ? *(const uint2*)(stg + (i - 480) * 256 + 2 * ep)
                    : *(const uint2*)(W0 + i * 256 + 2 * ep);
                const float uk = sh_u[i];    // wave-uniform broadcast
                float4 o;
                o.x = blo(tw.x) * uk * vv.x;
                o.y = bhi(tw.x) * uk * vv.y;
                o.z = blo(tw.y) * uk * vv.z;
                o.w = bhi(tw.y) * uk * vv.w;
                ob4[i * 128 + ep] = o;       // coalesced 16B/lane
            }
        }
    }
}

extern "C" void kernel_launch(void* const* d_in, const int* in_sizes, int n_in,
                              void* d_out, int out_size, void* d_ws, size_t ws_size,
                              hipStream_t stream) {
    const float* s     = (const float*)d_in[0];
    const int*   nrows = (const int*)d_in[1];
    const int*   ncols = (const int*)d_in[2];
    float*       out   = (float*)d_out;
    const int B = in_sizes[1];   // 256 batches, one 1024-thread block each
    sinkhorn_kernel<<<dim3(B), dim3(1024), 0, stream>>>(s, nrows, ncols, out);
}

// Round 8
// 733.817 us; speedup vs baseline: 1.8909x; 1.8909x over previous
//
#include <hip/hip_runtime.h>

// Sinkhorn-Knopp, factored: s_ij = a_ij * u_i * v_j; only u,v evolve.
// R10: R9 regressed (1086us): allocator kept the 8 register row-chunks
// (32 VGPR) at VGPR=64 and spilled the sweep ACCUMULATORS instead ->
// WRITE_SIZE 1.87GB (5.7KB/thread of loop spill), VALUBusy 8%.
// Lesson: the allocator will not give >~50 usefully-live VGPRs here.
// This round sizes the design to that reality:
//  - Register rows: 4 chunks (16 VGPR), rows 0..63. Sweep live set ~46.
//  - LDS rows: 128 (rows 64..191), 128KB; cpart shrunk 32->16KB via
//    two-step wave reduction (waves 0-7 store, waves 8-15 add, reduce).
//    Total LDS 148KB (same proven footprint as R9).
//  - Sweep global reads: rows 192..511 = 320KB/block/sweep (was 512KB
//    in the 371us R7; hot set 80MB).
//  - Epilogue: chunks 2..5 read LDS rows; chunk-15 stage reuses w_lds
//    bytes 0..32KB (rows 64..127, consumed by chunks 2,3 first).
//    Order: 2,3,4,5 | barrier | stage | 0,1,6,7 | per-chunk barrier 8..15.
#define SEPS 1e-10f
typedef unsigned int uu;

__device__ __forceinline__ uu bfpack2(float f0, float f1) {
    uu u0 = __float_as_uint(f0 + SEPS);
    uu u1 = __float_as_uint(f1 + SEPS);
    u0 += 0x7FFFu + ((u0 >> 16) & 1u);   // RNE to bf16
    u1 += 0x7FFFu + ((u1 >> 16) & 1u);
    return (u0 >> 16) | (u1 & 0xFFFF0000u);  // low16 = even col, high16 = odd col
}
__device__ __forceinline__ float blo(uu w){ return __uint_as_float(w << 16); }
__device__ __forceinline__ float bhi(uu w){ return __uint_as_float(w & 0xFFFF0000u); }
__device__ __forceinline__ float grcp(float x){ return (x > 0.f) ? __builtin_amdgcn_rcpf(x) : 1.f; }

__global__
__attribute__((amdgpu_flat_work_group_size(1024, 1024)))
void sinkhorn_kernel(const float* __restrict__ s, const int* __restrict__ nrows,
                     const int* __restrict__ ncols, float* __restrict__ out)
{
    __shared__ __align__(16) uu    w_lds[128 * 256];   // 128KB: W0 rows 64..191
    __shared__ __align__(16) float cpart[8][512];      // 16KB partials (two-step)
    __shared__ float sh_u[512];
    __shared__ float sh_v[512];

    const int b   = blockIdx.x;
    const int tid = threadIdx.x;
    const int wv  = tid >> 6;    // wave 0..15
    const int wl  = tid & 63;    // lane
    const int nr  = nrows[b];
    const int nc  = ncols[b];

    float* ob = out + ((size_t)b << 18);
    uu*    W0 = (uu*)ob + 131072;            // [512 rows][256 jpair] bf16 at out+512KB
    const float4* sb4 = (const float4*)(s + ((size_t)b << 18));
    float4* ob4 = (float4*)ob;

    // ---------------- phase A: pack+mask -> W0 (all rows), fused col partials (u=1)
    {
        const int p  = tid & 127;    // float4 col index (constant per thread)
        const int t8 = tid >> 7;     // 0..7 row phase
        const int rem = nc - 4 * p;
        const uu mA = (rem >= 2) ? 0xFFFFFFFFu : ((rem == 1) ? 0x0000FFFFu : 0u);
        const uu mB = (rem >= 4) ? 0xFFFFFFFFu : ((rem == 3) ? 0x0000FFFFu : 0u);
        float cA = 0.f, cB = 0.f, cC = 0.f, cD = 0.f;
        #pragma unroll 4
        for (int k = 0; k < 64; ++k) {
            const int r = (k << 3) + t8;
            float4 w = sb4[r * 128 + p];
            const uu rm = (r < nr) ? 0xFFFFFFFFu : 0u;
            const uu px = bfpack2(w.x, w.y) & mA & rm;
            const uu py = bfpack2(w.z, w.w) & mB & rm;
            *(uint2*)(W0 + r * 256 + 2 * p) = make_uint2(px, py);
            cA += blo(px); cB += bhi(px); cC += blo(py); cD += bhi(py);
        }
        *(float4*)&cpart[t8][4 * p] = make_float4(cA, cB, cC, cD);
    }
    __syncthreads();   // W0 + cpart visible block-wide

    // ---- fill LDS copy of rows 64..191 (8192 uint4, coalesced)
    {
        const uint4* s4 = (const uint4*)(W0 + 64 * 256);
        uint4* d4 = (uint4*)w_lds;
        #pragma unroll
        for (int it = 0; it < 8; ++it)
            d4[it * 1024 + tid] = s4[it * 1024 + tid];
    }
    // ---- register rows 0..63: row 16g+wv, lane wl holds jpair quad 4wl
    const uu* wp = W0 + wl * 4;
    uint4 R0 = *(const uint4*)(wp + ( 0 + wv) * 256);
    uint4 R1 = *(const uint4*)(wp + (16 + wv) * 256);
    uint4 R2 = *(const uint4*)(wp + (32 + wv) * 256);
    uint4 R3 = *(const uint4*)(wp + (48 + wv) * 256);

    if (tid < 512) {   // v1 from phase-A col partials
        float sum = cpart[0][tid] + cpart[1][tid] + cpart[2][tid] + cpart[3][tid]
                  + cpart[4][tid] + cpart[5][tid] + cpart[6][tid] + cpart[7][tid];
        sh_v[tid] = grcp(sum);
    }
    __syncthreads();   // w_lds + sh_v visible

    // fused row+col body for one row's quad wq
#define ROWF(wq) { \
    float p_ = blo(wq.x)*va.x + bhi(wq.x)*va.y + blo(wq.y)*va.z + bhi(wq.y)*va.w \
             + blo(wq.z)*vb.x + bhi(wq.z)*vb.y + blo(wq.w)*vb.z + bhi(wq.w)*vb.w; \
    p_ += __shfl_xor(p_, 1);  p_ += __shfl_xor(p_, 2);  p_ += __shfl_xor(p_, 4); \
    p_ += __shfl_xor(p_, 8);  p_ += __shfl_xor(p_, 16); p_ += __shfl_xor(p_, 32); \
    const float u_ = grcp(p_); \
    ce0 += blo(wq.x)*u_; co0 += bhi(wq.x)*u_; ce1 += blo(wq.y)*u_; co1 += bhi(wq.y)*u_; \
    ce2 += blo(wq.z)*u_; co2 += bhi(wq.z)*u_; ce3 += blo(wq.w)*u_; co3 += bhi(wq.w)*u_; }

    // ---------------- 9 fused sweeps: row(v)->u, col(u)->v'
    #pragma unroll 1
    for (int sw = 0; sw < 9; ++sw) {
        const float4 va = *(const float4*)&sh_v[wl * 8];
        const float4 vb = *(const float4*)&sh_v[wl * 8 + 4];
        float ce0=0,co0=0,ce1=0,co1=0,ce2=0,co2=0,ce3=0,co3=0;
        ROWF(R0) ROWF(R1) ROWF(R2) ROWF(R3)
        #pragma unroll
        for (int g = 4; g < 12; ++g) {
            uint4 wq = *(const uint4*)(w_lds + (16 * g + wv - 64) * 256 + wl * 4);
            ROWF(wq)
        }
        #pragma unroll 4
        for (int g = 12; g < 32; ++g) {
            uint4 wq = *(const uint4*)(wp + (16 * g + wv) * 256);
            ROWF(wq)
        }
        // two-step col-partial combine: waves 0-7 store, waves 8-15 add
        float* cw = &cpart[wv & 7][wl * 8];
        if (wv < 8) {
            cw[0]=ce0; cw[1]=co0; cw[2]=ce1; cw[3]=co1;
            cw[4]=ce2; cw[5]=co2; cw[6]=ce3; cw[7]=co3;
        }
        __syncthreads();
        if (wv >= 8) {
            cw[0]+=ce0; cw[1]+=co0; cw[2]+=ce1; cw[3]+=co1;
            cw[4]+=ce2; cw[5]+=co2; cw[6]+=ce3; cw[7]+=co3;
        }
        __syncthreads();
        if (tid < 512) {
            float sum = cpart[0][tid] + cpart[1][tid] + cpart[2][tid] + cpart[3][tid]
                      + cpart[4][tid] + cpart[5][tid] + cpart[6][tid] + cpart[7][tid];
            sh_v[tid] = grcp(sum);
        }
        __syncthreads();
    }

    // ---------------- final row-only pass: u10 from v10
#define FINROW(wq, i) { \
    float p_ = blo(wq.x)*va.x + bhi(wq.x)*va.y + blo(wq.y)*va.z + bhi(wq.y)*va.w \
             + blo(wq.z)*vb.x + bhi(wq.z)*vb.y + blo(wq.w)*vb.z + bhi(wq.w)*vb.w; \
    p_ += __shfl_xor(p_, 1);  p_ += __shfl_xor(p_, 2);  p_ += __shfl_xor(p_, 4); \
    p_ += __shfl_xor(p_, 8);  p_ += __shfl_xor(p_, 16); p_ += __shfl_xor(p_, 32); \
    if (wl == 0) sh_u[i] = grcp(p_); }
    {
        const float4 va = *(const float4*)&sh_v[wl * 8];
        const float4 vb = *(const float4*)&sh_v[wl * 8 + 4];
        FINROW(R0,  0 + wv) FINROW(R1, 16 + wv) FINROW(R2, 32 + wv) FINROW(R3, 48 + wv)
        #pragma unroll
        for (int g = 4; g < 12; ++g) {
            uint4 wq = *(const uint4*)(w_lds + (16 * g + wv - 64) * 256 + wl * 4);
            FINROW(wq, 16 * g + wv)
        }
        #pragma unroll 4
        for (int g = 12; g < 32; ++g) {
            uint4 wq = *(const uint4*)(wp + (16 * g + wv) * 256);
            FINROW(wq, 16 * g + wv)
        }
    }
    __syncthreads();   // sh_u visible; all sweep reads complete

    // ---------------- epilogue: out = a * u_i * v_j
    {
        const int ep = tid & 127;   // float4 index within a row
        const int rs = tid >> 7;    // 0..7, wave-uniform
        const float4 vv = make_float4(sh_v[4*ep], sh_v[4*ep+1], sh_v[4*ep+2], sh_v[4*ep+3]);

#define EPCHUNK(m, SRC) { \
        _Pragma("unroll") \
        for (int it = 0; it < 4; ++it) { \
            const int i = ((m) << 5) + (it << 3) + rs; \
            const uint2 tw = SRC; \
            const float uk = sh_u[i]; \
            float4 o; \
            o.x = blo(tw.x) * uk * vv.x; \
            o.y = bhi(tw.x) * uk * vv.y; \
            o.z = blo(tw.y) * uk * vv.z; \
            o.w = bhi(tw.y) * uk * vv.w; \
            ob4[i * 128 + ep] = o; \
        } }

        // chunks 2..5 from LDS rows 64..191 (out bytes 128K..384K, no W0 overlap)
        EPCHUNK(2, (*(const uint2*)(w_lds + (i - 64) * 256 + 2 * ep)))
        EPCHUNK(3, (*(const uint2*)(w_lds + (i - 64) * 256 + 2 * ep)))
        EPCHUNK(4, (*(const uint2*)(w_lds + (i - 64) * 256 + 2 * ep)))
        EPCHUNK(5, (*(const uint2*)(w_lds + (i - 64) * 256 + 2 * ep)))
        __syncthreads();   // LDS rows 64..127 now dead; safe to reuse as stage
        // stage W0 rows 480..511 (32KB) into w_lds[0..8K uu)
        {
            uint4* d4 = (uint4*)w_lds;
            const uint4* s4 = (const uint4*)(W0 + 480 * 256);
            d4[tid]        = s4[tid];
            d4[tid + 1024] = s4[tid + 1024];
        }
        __syncthreads();
        // chunks 0,1,6,7 from W0 (writes stay below byte 512K, no W0 overlap)
        EPCHUNK(0, (*(const uint2*)(W0 + i * 256 + 2 * ep)))
        EPCHUNK(1, (*(const uint2*)(W0 + i * 256 + 2 * ep)))
        EPCHUNK(6, (*(const uint2*)(W0 + i * 256 + 2 * ep)))
        EPCHUNK(7, (*(const uint2*)(W0 + i * 256 + 2 * ep)))
        // chunks 8..14 overwrite W0 rows 64(m-8)..+63, whose readers
        // (chunks 2m-16, 2m-15) all precede m in this order; barrier each.
        #pragma unroll 1
        for (int m = 8; m < 15; ++m) {
            __syncthreads();
            EPCHUNK(m, (*(const uint2*)(W0 + i * 256 + 2 * ep)))
        }
        __syncthreads();
        EPCHUNK(15, (*(const uint2*)((uu*)w_lds + (i - 480) * 256 + 2 * ep)))
    }
}

extern "C" void kernel_launch(void* const* d_in, const int* in_sizes, int n_in,
                              void* d_out, int out_size, void* d_ws, size_t ws_size,
                              hipStream_t stream) {
    const float* s     = (const float*)d_in[0];
    const int*   nrows = (const int*)d_in[1];
    const int*   ncols = (const int*)d_in[2];
    float*       out   = (float*)d_out;
    const int B = in_sizes[1];   // 256 batches, one 1024-thread block each
    sinkhorn_kernel<<<dim3(B), dim3(1024), 0, stream>>>(s, nrows, ncols, out);
}

// Round 10
// 626.704 us; speedup vs baseline: 2.2141x; 1.1709x over previous
//
#include <hip/hip_runtime.h>

// Sinkhorn-Knopp, factored: s_ij = a_ij * u_i * v_j; only u,v evolve.
// R12 = R11 minus __builtin_nontemporal_load. Container-failure forensics:
// R6 and R9 both used nontemporal builtins and both died; R4/R5/R7/R8
// (no nontemporal) all ran. Blacklisted. Boustrophedon ordering retained:
//  - phase A fills W0 running k BACKWARD (ends with head rows hot);
//  - sweeps alternate fwd/bwd (sweep0 fwd ... sweep8 fwd);
//  - final row pass bwd; epilogue fwd.
// Every pass starts where the previous pass ended -> reuse-distance-0 at
// each boundary, reclaiming the ~650MB of cyclic-scan L3 thrash misses
// that R7's FETCH=913MB (vs 256MB compulsory) exposed.
// Base is otherwise the proven 371us R7 kernel (36KB LDS, VGPR~36).
#define SEPS 1e-10f
typedef unsigned int uu;

__device__ __forceinline__ uu bfpack2(float f0, float f1) {
    uu u0 = __float_as_uint(f0 + SEPS);
    uu u1 = __float_as_uint(f1 + SEPS);
    u0 += 0x7FFFu + ((u0 >> 16) & 1u);   // RNE to bf16
    u1 += 0x7FFFu + ((u1 >> 16) & 1u);
    return (u0 >> 16) | (u1 & 0xFFFF0000u);  // low16 = even col, high16 = odd col
}
__device__ __forceinline__ float blo(uu w){ return __uint_as_float(w << 16); }
__device__ __forceinline__ float bhi(uu w){ return __uint_as_float(w & 0xFFFF0000u); }
__device__ __forceinline__ float grcp(float x){ return (x > 0.f) ? __builtin_amdgcn_rcpf(x) : 1.f; }

__global__
__attribute__((amdgpu_flat_work_group_size(1024, 1024)))
void sinkhorn_kernel(const float* __restrict__ s, const int* __restrict__ nrows,
                     const int* __restrict__ ncols, float* __restrict__ out)
{
    __shared__ __align__(16) float cpart[16][512];   // 32KB col partials; epilogue stage reuse
    __shared__ float sh_u[512];
    __shared__ float sh_v[512];

    const int b   = blockIdx.x;
    const int tid = threadIdx.x;
    const int wv  = tid >> 6;    // wave 0..15
    const int wl  = tid & 63;    // lane
    const int nr  = nrows[b];
    const int nc  = ncols[b];

    float* ob = out + ((size_t)b << 18);
    uu*    W0 = (uu*)ob + 131072;            // [512 rows][256 jpair] bf16 at out+512KB
    const float4* sb4 = (const float4*)(s + ((size_t)b << 18));
    float4* ob4 = (float4*)ob;

    // ---------------- phase A: pack+mask -> W0, fused col partials (u=1)
    // k runs BACKWARD so phase A ends with W0 head rows hot in L3 (sweep0 is fwd)
    {
        const int p  = tid & 127;    // float4 col index (constant per thread)
        const int t8 = tid >> 7;     // 0..7 row phase
        const int rem = nc - 4 * p;
        const uu mA = (rem >= 2) ? 0xFFFFFFFFu : ((rem == 1) ? 0x0000FFFFu : 0u);
        const uu mB = (rem >= 4) ? 0xFFFFFFFFu : ((rem == 3) ? 0x0000FFFFu : 0u);
        float cA = 0.f, cB = 0.f, cC = 0.f, cD = 0.f;
        #pragma unroll 4
        for (int k = 63; k >= 0; --k) {
            const int r = (k << 3) + t8;
            float4 w = sb4[r * 128 + p];
            const uu rm = (r < nr) ? 0xFFFFFFFFu : 0u;
            const uu px = bfpack2(w.x, w.y) & mA & rm;
            const uu py = bfpack2(w.z, w.w) & mB & rm;
            *(uint2*)(W0 + r * 256 + 2 * p) = make_uint2(px, py);
            cA += blo(px); cB += bhi(px); cC += blo(py); cD += bhi(py);
        }
        *(float4*)&cpart[t8][4 * p] = make_float4(cA, cB, cC, cD);
    }
    __syncthreads();   // W0 + cpart visible

    const uu* wp = W0 + wl * 4;   // this lane's jpair quad base (cols 8wl..8wl+7)

    if (tid < 512) {   // v1 from phase-A col partials
        float sum = cpart[0][tid] + cpart[1][tid] + cpart[2][tid] + cpart[3][tid]
                  + cpart[4][tid] + cpart[5][tid] + cpart[6][tid] + cpart[7][tid];
        sh_v[tid] = grcp(sum);
    }
    __syncthreads();

    // fused row+col body for one row's quad wq
#define ROWF(wq) { \
    float p_ = blo(wq.x)*va.x + bhi(wq.x)*va.y + blo(wq.y)*va.z + bhi(wq.y)*va.w \
             + blo(wq.z)*vb.x + bhi(wq.z)*vb.y + blo(wq.w)*vb.z + bhi(wq.w)*vb.w; \
    p_ += __shfl_xor(p_, 1);  p_ += __shfl_xor(p_, 2);  p_ += __shfl_xor(p_, 4); \
    p_ += __shfl_xor(p_, 8);  p_ += __shfl_xor(p_, 16); p_ += __shfl_xor(p_, 32); \
    const float u_ = grcp(p_); \
    ce0 += blo(wq.x)*u_; co0 += bhi(wq.x)*u_; ce1 += blo(wq.y)*u_; co1 += bhi(wq.y)*u_; \
    ce2 += blo(wq.z)*u_; co2 += bhi(wq.z)*u_; ce3 += blo(wq.w)*u_; co3 += bhi(wq.w)*u_; }

    // ---------------- 9 fused sweeps: row(v)->u, col(u)->v', zigzag direction
    #pragma unroll 1
    for (int sw = 0; sw < 9; ++sw) {
        const float4 va = *(const float4*)&sh_v[wl * 8];
        const float4 vb = *(const float4*)&sh_v[wl * 8 + 4];
        float ce0=0,co0=0,ce1=0,co1=0,ce2=0,co2=0,ce3=0,co3=0;
        if ((sw & 1) == 0) {
            #pragma unroll 4
            for (int g = 0; g < 32; ++g) {
                uint4 wq = *(const uint4*)(wp + ((g << 4) + wv) * 256);
                ROWF(wq)
            }
        } else {
            #pragma unroll 4
            for (int g = 31; g >= 0; --g) {
                uint4 wq = *(const uint4*)(wp + ((g << 4) + wv) * 256);
                ROWF(wq)
            }
        }
        float* cw = &cpart[wv][wl * 8];
        cw[0]=ce0; cw[1]=co0; cw[2]=ce1; cw[3]=co1;
        cw[4]=ce2; cw[5]=co2; cw[6]=ce3; cw[7]=co3;
        __syncthreads();
        if (tid < 512) {
            float sum = 0.f;
            #pragma unroll
            for (int w = 0; w < 16; ++w) sum += cpart[w][tid];
            sh_v[tid] = grcp(sum);
        }
        __syncthreads();
    }

    // ---------------- final row-only pass (BACKWARD): u10 from v10
    {
        const float4 va = *(const float4*)&sh_v[wl * 8];
        const float4 vb = *(const float4*)&sh_v[wl * 8 + 4];
        #pragma unroll 4
        for (int g = 31; g >= 0; --g) {
            const int i = (g << 4) + wv;
            uint4 wq = *(const uint4*)(wp + i * 256);
            float p_ = blo(wq.x)*va.x + bhi(wq.x)*va.y + blo(wq.y)*va.z + bhi(wq.y)*va.w
                     + blo(wq.z)*vb.x + bhi(wq.z)*vb.y + blo(wq.w)*vb.z + bhi(wq.w)*vb.w;
            p_ += __shfl_xor(p_, 1);  p_ += __shfl_xor(p_, 2);  p_ += __shfl_xor(p_, 4);
            p_ += __shfl_xor(p_, 8);  p_ += __shfl_xor(p_, 16); p_ += __shfl_xor(p_, 32);
            if (wl == 0) sh_u[i] = grcp(p_);
        }
    }
    __syncthreads();   // sh_u visible; all sweep reads of W0 complete

    // ---------------- epilogue (FORWARD): out = a * u_i * v_j from W0
    // stage W0 rows 480..511 (32KB) into cpart before any overwrite
    uu* stg = (uu*)cpart;
    {
        uint4* d4 = (uint4*)stg;
        const uint4* s4 = (const uint4*)(W0 + 480 * 256);
        d4[tid]        = s4[tid];
        d4[tid + 1024] = s4[tid + 1024];
    }
    __syncthreads();
    {
        const int ep = tid & 127;   // float4 index within a row
        const int rs = tid >> 7;    // 0..7, wave-uniform
        const float4 vv = make_float4(sh_v[4*ep], sh_v[4*ep+1], sh_v[4*ep+2], sh_v[4*ep+3]);
        #pragma unroll 1
        for (int m = 0; m < 16; ++m) {
            if (m >= 8) __syncthreads();   // chunks < m done before their W0 rows die
            #pragma unroll
            for (int it = 0; it < 4; ++it) {
                const int i = (m << 5) + (it << 3) + rs;
                const uint2 tw = (m == 15)
                    ? *(const uint2*)(stg + (i - 480) * 256 + 2 * ep)
                    : *(const uint2*)(W0 + i * 256 + 2 * ep);
                const float uk = sh_u[i];    // wave-uniform broadcast
                float4 o;
                o.x = blo(tw.x) * uk * vv.x;
                o.y = bhi(tw.x) * uk * vv.y;
                o.z = blo(tw.y) * uk * vv.z;
                o.w = bhi(tw.y) * uk * vv.w;
                ob4[i * 128 + ep] = o;       // coalesced 16B/lane
            }
        }
    }
}

extern "C" void kernel_launch(void* const* d_in, const int* in_sizes, int n_in,
                              void* d_out, int out_size, void* d_ws, size_t ws_size,
                              hipStream_t stream) {
    const float* s     = (const float*)d_in[0];
    const int*   nrows = (const int*)d_in[1];
    const int*   ncols = (const int*)d_in[2];
    float*       out   = (float*)d_out;
    const int B = in_sizes[1];   // 256 batches, one 1024-thread block each
    sinkhorn_kernel<<<dim3(B), dim3(1024), 0, stream>>>(s, nrows, ncols, out);
}